// Round 3
// baseline (664.175 us; speedup 1.0000x reference)
//
#include <hip/hip_runtime.h>

// z = segment_sum(x[col], row) @ W.T    (softmax over [E,1] axis=1 == 1)
// Bucketed counting sort by destination (64 rows/bucket) + per-bucket LDS
// accumulation + fused transform. All fp adds via LDS ds_add_f32.

#define NBMAX 1600   // buckets = ceil(N/64); N=100000 -> 1563

__global__ __launch_bounds__(1024) void k_ghist(const int* __restrict__ ei,
                                                int* __restrict__ gcnt,
                                                int E, int NB) {
    __shared__ int h[NBMAX];
    for (int i = threadIdx.x; i < NB; i += 1024) h[i] = 0;
    __syncthreads();
    long stride = (long)gridDim.x * 1024;
    for (long i = (long)blockIdx.x * 1024 + threadIdx.x; i < E; i += stride)
        atomicAdd(&h[ei[i] >> 6], 1);
    __syncthreads();
    for (int i = threadIdx.x; i < NB; i += 1024) {
        int v = h[i];
        if (v) atomicAdd(&gcnt[i], v);
    }
}

__global__ __launch_bounds__(1024) void k_gscan(const int* __restrict__ gcnt,
                                                int* __restrict__ boff,
                                                int* __restrict__ gcur,
                                                int NB, int E) {
    __shared__ int a[2048], b2[2048];
    int t = threadIdx.x;
    for (int i = t; i < 2048; i += 1024) a[i] = (i < NB) ? gcnt[i] : 0;
    __syncthreads();
    int* src = a; int* dst = b2;
    for (int s = 1; s < 2048; s <<= 1) {
        for (int i = t; i < 2048; i += 1024)
            dst[i] = src[i] + ((i >= s) ? src[i - s] : 0);
        __syncthreads();
        int* tmp = src; src = dst; dst = tmp;
    }
    for (int i = t; i < NB; i += 1024) {
        int excl = src[i] - gcnt[i];
        boff[i] = excl;
        gcur[i] = excl;
    }
    if (t == 0) boff[NB] = E;
}

// chunk = 8192 edges; LDS hist -> one global atomic per (chunk,bucket) ->
// LDS-cursor scatter of packed 4B records: (row&63)<<26 | col.
__global__ __launch_bounds__(1024) void k_pairs(const int* __restrict__ ei,
                                                int* __restrict__ gcur,
                                                unsigned* __restrict__ pairs,
                                                int E, int NB) {
    __shared__ int hist[NBMAX];
    int t = threadIdx.x;
    long cb = (long)blockIdx.x * 8192;
    for (int i = t; i < NB; i += 1024) hist[i] = 0;
    int rows[8], cols[8];
    #pragma unroll
    for (int u = 0; u < 8; ++u) {
        long i = cb + (long)u * 1024 + t;
        rows[u] = (i < E) ? ei[i] : -1;
        cols[u] = (i < E) ? ei[(long)E + i] : 0;
    }
    __syncthreads();
    #pragma unroll
    for (int u = 0; u < 8; ++u)
        if (rows[u] >= 0) atomicAdd(&hist[rows[u] >> 6], 1);
    __syncthreads();
    for (int b = t; b < NB; b += 1024) {
        int c = hist[b];
        hist[b] = c ? atomicAdd(&gcur[b], c) : 0;
    }
    __syncthreads();
    #pragma unroll
    for (int u = 0; u < 8; ++u)
        if (rows[u] >= 0) {
            int p = atomicAdd(&hist[rows[u] >> 6], 1);
            pairs[p] = ((unsigned)(rows[u] & 63) << 26) | (unsigned)cols[u];
        }
}

// Block per bucket: LDS-accumulate 64 rows, then fused @W.T + coalesced write.
__global__ __launch_bounds__(256) void k_accum(const float* __restrict__ x,
                                               const unsigned* __restrict__ pairs,
                                               const int* __restrict__ boff,
                                               const float* __restrict__ W,
                                               float* __restrict__ out, int N) {
    __shared__ float acc[64][64];
    __shared__ float w[64][65];   // (65c+k)%32 = (c+k)%32 -> 2-way alias only (free)
    int t = threadIdx.x, lane = t & 63, wv = t >> 6;
    for (int i = t; i < 4096; i += 256) w[i >> 6][i & 63] = W[i];
    for (int i = t; i < 4096; i += 256) ((float*)acc)[i] = 0.f;
    __syncthreads();
    int b = blockIdx.x;
    int s = boff[b], e = boff[b + 1];
    for (int j0 = s + wv * 4; j0 < e; j0 += 16) {
        int m = e - j0;
        unsigned pv[4]; float xv[4];
        #pragma unroll
        for (int u = 0; u < 4; ++u) pv[u] = (u < m) ? pairs[j0 + u] : 0u;
        #pragma unroll
        for (int u = 0; u < 4; ++u)
            xv[u] = (u < m) ? x[(long)(pv[u] & 0x3FFFFFFu) * 64 + lane] : 0.f;
        #pragma unroll
        for (int u = 0; u < 4; ++u)
            if (u < m) atomicAdd(&acc[pv[u] >> 26][lane], xv[u]);  // ds_add_f32
    }
    __syncthreads();
    int base = b << 6;
    int nr = N - base; if (nr > 64) nr = 64;
    for (int r = wv; r < nr; r += 4) {
        float z = 0.f;
        #pragma unroll
        for (int k = 0; k < 64; ++k)
            z += acc[r][k] * w[lane][k];   // acc[r][k] wave-uniform -> broadcast
        out[(long)(base + r) * 64 + lane] = z;
    }
}

// ---- fallback (atomic scatter, R1 path) ----
__global__ __launch_bounds__(256) void egat_scatter(const float* __restrict__ x,
                                                    const int* __restrict__ ei,
                                                    float* __restrict__ out, int E) {
    long tid = (long)blockIdx.x * blockDim.x + threadIdx.x;
    long e = tid >> 4;
    if (e >= E) return;
    int c4 = (int)(tid & 15) << 2;
    int row = ei[e];
    int col = ei[(long)E + e];
    const float4 v = *reinterpret_cast<const float4*>(x + (long)col * 64 + c4);
    float* o = out + (long)row * 64 + c4;
    atomicAdd(o + 0, v.x); atomicAdd(o + 1, v.y);
    atomicAdd(o + 2, v.z); atomicAdd(o + 3, v.w);
}

__global__ __launch_bounds__(256) void egat_transform(float* __restrict__ out,
                                                      const float* __restrict__ W, int N) {
    __shared__ float a[16][64];
    __shared__ float w[64][65];
    int t = threadIdx.x;
    for (int i = t; i < 64 * 64; i += 256) w[i >> 6][i & 63] = W[i];
    long r0 = (long)blockIdx.x * 16;
    int c = t & 63, rb = t >> 6;
    #pragma unroll
    for (int j = 0; j < 4; ++j) {
        long r = r0 + rb + 4 * j;
        if (r < N) a[rb + 4 * j][c] = out[r * 64 + c];
    }
    __syncthreads();
    float acc[4] = {0.f, 0.f, 0.f, 0.f};
    #pragma unroll
    for (int k = 0; k < 64; ++k) {
        float wk = w[c][k];
        #pragma unroll
        for (int j = 0; j < 4; ++j) acc[j] += a[rb + 4 * j][k] * wk;
    }
    #pragma unroll
    for (int j = 0; j < 4; ++j) {
        long r = r0 + rb + 4 * j;
        if (r < N) out[r * 64 + c] = acc[j];
    }
}

extern "C" void kernel_launch(void* const* d_in, const int* in_sizes, int n_in,
                              void* d_out, int out_size, void* d_ws, size_t ws_size,
                              hipStream_t stream)
{
    const float* x  = (const float*)d_in[0];
    const int*   ei = (const int*)d_in[1];
    const float* W  = (const float*)d_in[3];
    float* out = (float*)d_out;

    const int E  = in_sizes[1] / 2;
    const int N  = out_size / 64;
    const int NB = (N + 63) >> 6;

    // ws layout: gcnt[NB] | boff[NB+1] | gcur[NB] | pairs[E]
    size_t need = ((size_t)NB * 3 + 1 + E) * sizeof(int);
    if (NB <= NBMAX && ws_size >= need) {
        int* gcnt = (int*)d_ws;
        int* boff = gcnt + NB;
        int* gcur = boff + (NB + 1);
        unsigned* pairs = (unsigned*)(gcur + NB);

        hipMemsetAsync(gcnt, 0, (size_t)NB * sizeof(int), stream);
        k_ghist<<<128, 1024, 0, stream>>>(ei, gcnt, E, NB);
        k_gscan<<<1, 1024, 0, stream>>>(gcnt, boff, gcur, NB, E);
        k_pairs<<<(E + 8191) / 8192, 1024, 0, stream>>>(ei, gcur, pairs, E, NB);
        k_accum<<<NB, 256, 0, stream>>>(x, pairs, boff, W, out, N);
    } else {
        hipMemsetAsync(out, 0, (size_t)N * 64 * sizeof(float), stream);
        long sthreads = (long)E * 16;
        egat_scatter<<<(int)((sthreads + 255) / 256), 256, 0, stream>>>(x, ei, out, E);
        egat_transform<<<(N + 15) / 16, 256, 0, stream>>>(out, W, N);
    }
}

// Round 4
// 204.409 us; speedup vs baseline: 3.2493x; 3.2493x over previous
//
#include <hip/hip_runtime.h>

// z = segment_sum(x[col], row) @ W.T    (softmax over [E,1] axis=1 == 1)
// Bucket build (cheap, ~34us measured in R3) + per-bucket LDS counting sort
// + register-accumulate gather (no fp atomics anywhere) + fused transform.

#define NBMAX 1600   // buckets = ceil(N/64); N=100000 -> 1563
#define BCAP  2048   // per-tile edge capacity in k_bgather (mean/bucket ~1024)

__global__ __launch_bounds__(1024) void k_ghist(const int* __restrict__ ei,
                                                int* __restrict__ gcnt,
                                                int E, int NB) {
    __shared__ int h[NBMAX];
    for (int i = threadIdx.x; i < NB; i += 1024) h[i] = 0;
    __syncthreads();
    long stride = (long)gridDim.x * 1024;
    for (long i = (long)blockIdx.x * 1024 + threadIdx.x; i < E; i += stride)
        atomicAdd(&h[ei[i] >> 6], 1);
    __syncthreads();
    for (int i = threadIdx.x; i < NB; i += 1024) {
        int v = h[i];
        if (v) atomicAdd(&gcnt[i], v);
    }
}

__global__ __launch_bounds__(1024) void k_gscan(const int* __restrict__ gcnt,
                                                int* __restrict__ boff,
                                                int* __restrict__ gcur,
                                                int NB, int E) {
    __shared__ int a[2048], b2[2048];
    int t = threadIdx.x;
    for (int i = t; i < 2048; i += 1024) a[i] = (i < NB) ? gcnt[i] : 0;
    __syncthreads();
    int* src = a; int* dst = b2;
    for (int s = 1; s < 2048; s <<= 1) {
        for (int i = t; i < 2048; i += 1024)
            dst[i] = src[i] + ((i >= s) ? src[i - s] : 0);
        __syncthreads();
        int* tmp = src; src = dst; dst = tmp;
    }
    for (int i = t; i < NB; i += 1024) {
        int excl = src[i] - gcnt[i];
        boff[i] = excl;
        gcur[i] = excl;
    }
    if (t == 0) boff[NB] = E;
}

// chunk = 8192 edges; LDS hist -> one global atomic per (chunk,bucket) ->
// LDS-cursor scatter of packed 4B records: (row&63)<<26 | col.
__global__ __launch_bounds__(1024) void k_pairs(const int* __restrict__ ei,
                                                int* __restrict__ gcur,
                                                unsigned* __restrict__ pairs,
                                                int E, int NB) {
    __shared__ int hist[NBMAX];
    int t = threadIdx.x;
    long cb = (long)blockIdx.x * 8192;
    for (int i = t; i < NB; i += 1024) hist[i] = 0;
    int rows[8], cols[8];
    #pragma unroll
    for (int u = 0; u < 8; ++u) {
        long i = cb + (long)u * 1024 + t;
        rows[u] = (i < E) ? ei[i] : -1;
        cols[u] = (i < E) ? ei[(long)E + i] : 0;
    }
    __syncthreads();
    #pragma unroll
    for (int u = 0; u < 8; ++u)
        if (rows[u] >= 0) atomicAdd(&hist[rows[u] >> 6], 1);
    __syncthreads();
    for (int b = t; b < NB; b += 1024) {
        int c = hist[b];
        hist[b] = c ? atomicAdd(&gcur[b], c) : 0;
    }
    __syncthreads();
    #pragma unroll
    for (int u = 0; u < 8; ++u)
        if (rows[u] >= 0) {
            int p = atomicAdd(&hist[rows[u] >> 6], 1);
            pairs[p] = ((unsigned)(rows[u] & 63) << 26) | (unsigned)cols[u];
        }
}

// Block (16 waves) per bucket: LDS counting-sort pairs by row, then each wave
// register-accumulates rows {wv, wv+16, wv+32, wv+48}; fused @W.T epilogue.
__global__ __launch_bounds__(1024, 8) void k_bgather(
    const float* __restrict__ x, const unsigned* __restrict__ pairs,
    const int* __restrict__ boff, const float* __restrict__ W,
    float* __restrict__ out, int N)
{
    __shared__ float w[64][65];       // 16.6KB; (65c+k)%32=(c+k)%32 -> 2-way only
    __shared__ float rowacc[64][64];  // 16KB
    __shared__ unsigned spv[BCAP];    // 8KB  staged packed pairs
    __shared__ int scol[BCAP];        // 8KB  row-sorted cols
    __shared__ int cnt[64];
    __shared__ int cs[65];
    int t = threadIdx.x, lane = t & 63, wv = t >> 6;   // 16 waves
    for (int i = t; i < 4096; i += 1024) w[i >> 6][i & 63] = W[i];
    int b = blockIdx.x;
    int s = boff[b], e = boff[b + 1];
    float acc[4] = {0.f, 0.f, 0.f, 0.f};

    for (int tile = s; tile < e; tile += BCAP) {
        int m = e - tile; if (m > BCAP) m = BCAP;
        if (t < 64) cnt[t] = 0;
        __syncthreads();
        for (int i = t; i < m; i += 1024) {
            unsigned pv = pairs[tile + i];
            spv[i] = pv;
            atomicAdd(&cnt[pv >> 26], 1);
        }
        __syncthreads();
        if (wv == 0) {                       // 64-wide exclusive scan, wave 0
            int c0 = cnt[lane];
            int v = c0;
            #pragma unroll
            for (int o = 1; o < 64; o <<= 1) {
                int u = __shfl_up(v, o, 64);
                if (lane >= o) v += u;
            }
            cs[lane + 1] = v;
            if (lane == 0) cs[0] = 0;
            cnt[lane] = v - c0;              // cursor = exclusive prefix
        }
        __syncthreads();
        for (int i = t; i < m; i += 1024) {
            unsigned pv = spv[i];
            int p = atomicAdd(&cnt[pv >> 26], 1);
            scol[p] = (int)(pv & 0x3FFFFFFu);
        }
        __syncthreads();
        #pragma unroll
        for (int rr = 0; rr < 4; ++rr) {
            int r = wv + (rr << 4);
            int rs = cs[r], re = cs[r + 1];
            int j = rs;
            for (; j + 4 <= re; j += 4) {    // 4-deep MLP on the gather chain
                int c0 = scol[j], c1 = scol[j + 1], c2 = scol[j + 2], c3 = scol[j + 3];
                float v0 = x[(long)c0 * 64 + lane];
                float v1 = x[(long)c1 * 64 + lane];
                float v2 = x[(long)c2 * 64 + lane];
                float v3 = x[(long)c3 * 64 + lane];
                acc[rr] += (v0 + v1) + (v2 + v3);
            }
            for (; j < re; ++j) acc[rr] += x[(long)scol[j] * 64 + lane];
        }
        __syncthreads();                     // protect cnt/cs/spv/scol for next tile
    }

    #pragma unroll
    for (int rr = 0; rr < 4; ++rr) rowacc[wv + (rr << 4)][lane] = acc[rr];
    __syncthreads();
    int base = b << 6;
    int nr = N - base; if (nr > 64) nr = 64;
    for (int r = wv; r < nr; r += 16) {
        float z = 0.f;
        #pragma unroll
        for (int k = 0; k < 64; ++k)
            z += rowacc[r][k] * w[lane][k];  // rowacc[r][k] wave-uniform -> broadcast
        out[(long)(base + r) * 64 + lane] = z;
    }
}

// ---- fallback (atomic scatter, R1 path) ----
__global__ __launch_bounds__(256) void egat_scatter(const float* __restrict__ x,
                                                    const int* __restrict__ ei,
                                                    float* __restrict__ out, int E) {
    long tid = (long)blockIdx.x * blockDim.x + threadIdx.x;
    long e = tid >> 4;
    if (e >= E) return;
    int c4 = (int)(tid & 15) << 2;
    int row = ei[e];
    int col = ei[(long)E + e];
    const float4 v = *reinterpret_cast<const float4*>(x + (long)col * 64 + c4);
    float* o = out + (long)row * 64 + c4;
    atomicAdd(o + 0, v.x); atomicAdd(o + 1, v.y);
    atomicAdd(o + 2, v.z); atomicAdd(o + 3, v.w);
}

__global__ __launch_bounds__(256) void egat_transform(float* __restrict__ out,
                                                      const float* __restrict__ W, int N) {
    __shared__ float a[16][64];
    __shared__ float w[64][65];
    int t = threadIdx.x;
    for (int i = t; i < 64 * 64; i += 256) w[i >> 6][i & 63] = W[i];
    long r0 = (long)blockIdx.x * 16;
    int c = t & 63, rb = t >> 6;
    #pragma unroll
    for (int j = 0; j < 4; ++j) {
        long r = r0 + rb + 4 * j;
        if (r < N) a[rb + 4 * j][c] = out[r * 64 + c];
    }
    __syncthreads();
    float acc[4] = {0.f, 0.f, 0.f, 0.f};
    #pragma unroll
    for (int k = 0; k < 64; ++k) {
        float wk = w[c][k];
        #pragma unroll
        for (int j = 0; j < 4; ++j) acc[j] += a[rb + 4 * j][k] * wk;
    }
    #pragma unroll
    for (int j = 0; j < 4; ++j) {
        long r = r0 + rb + 4 * j;
        if (r < N) out[r * 64 + c] = acc[j];
    }
}

extern "C" void kernel_launch(void* const* d_in, const int* in_sizes, int n_in,
                              void* d_out, int out_size, void* d_ws, size_t ws_size,
                              hipStream_t stream)
{
    const float* x  = (const float*)d_in[0];
    const int*   ei = (const int*)d_in[1];
    const float* W  = (const float*)d_in[3];
    float* out = (float*)d_out;

    const int E  = in_sizes[1] / 2;
    const int N  = out_size / 64;
    const int NB = (N + 63) >> 6;

    // ws layout: gcnt[NB] | boff[NB+1] | gcur[NB] | pairs[E]
    size_t need = ((size_t)NB * 3 + 1 + E) * sizeof(int);
    if (NB <= NBMAX && ws_size >= need) {
        int* gcnt = (int*)d_ws;
        int* boff = gcnt + NB;
        int* gcur = boff + (NB + 1);
        unsigned* pairs = (unsigned*)(gcur + NB);

        hipMemsetAsync(gcnt, 0, (size_t)NB * sizeof(int), stream);
        k_ghist<<<128, 1024, 0, stream>>>(ei, gcnt, E, NB);
        k_gscan<<<1, 1024, 0, stream>>>(gcnt, boff, gcur, NB, E);
        k_pairs<<<(E + 8191) / 8192, 1024, 0, stream>>>(ei, gcur, pairs, E, NB);
        k_bgather<<<NB, 1024, 0, stream>>>(x, pairs, boff, W, out, N);
    } else {
        hipMemsetAsync(out, 0, (size_t)N * 64 * sizeof(float), stream);
        long sthreads = (long)E * 16;
        egat_scatter<<<(int)((sthreads + 255) / 256), 256, 0, stream>>>(x, ei, out, E);
        egat_transform<<<(N + 15) / 16, 256, 0, stream>>>(out, W, N);
    }
}